// Round 1
// baseline (6898.643 us; speedup 1.0000x reference)
//
#include <hip/hip_runtime.h>
#include <cstddef>

typedef __attribute__((ext_vector_type(8))) short short8;
typedef __attribute__((ext_vector_type(4))) short short4v;
typedef __attribute__((ext_vector_type(4))) float f32x4;

__device__ __forceinline__ unsigned short f2bf(float f){
  unsigned u = __builtin_bit_cast(unsigned, f);
  u += 0x7FFFu + ((u >> 16) & 1u);          // round-to-nearest-even
  return (unsigned short)(u >> 16);
}
__device__ __forceinline__ float bf2f(unsigned short h){
  unsigned u = ((unsigned)h) << 16;
  return __builtin_bit_cast(float, u);
}
__device__ __forceinline__ float sigf(float x){
  return __builtin_amdgcn_rcpf(1.0f + __builtin_amdgcn_exp2f(-1.4426950408889634f * x));
}
__device__ __forceinline__ float tanhf_(float x){
  return 1.0f - 2.0f * __builtin_amdgcn_rcpf(1.0f + __builtin_amdgcn_exp2f(2.8853900817779268f * x));
}

// inputs [32][1024][256] fp32 -> xbf [t*32+b][256] bf16
__global__ __launch_bounds__(64) void cast_x(const float* __restrict__ in, unsigned short* __restrict__ xb){
  int blk = blockIdx.x;              // b*1024 + t
  int t = blk & 1023, b = blk >> 10;
  int k = threadIdx.x * 4;
  float4 v = *(const float4*)(in + (size_t)blk * 256 + k);
  unsigned lo = f2bf(v.x) | ((unsigned)f2bf(v.y) << 16);
  unsigned hi = f2bf(v.z) | ((unsigned)f2bf(v.w) << 16);
  *(uint2*)(xb + ((size_t)t * 32 + b) * 256 + k) = make_uint2(lo, hi);
}

// Wih (fw,bw) fp32 -> Bw [2048][K] bf16 (row = dir*1024 + gatecol), bias[row] = bih+bhh
__global__ __launch_bounds__(64) void cast_w(const float* __restrict__ Wf, const float* __restrict__ Wb,
    const float* __restrict__ bihf, const float* __restrict__ bhhf,
    const float* __restrict__ bihb, const float* __restrict__ bhhb,
    unsigned short* __restrict__ Bw, float* __restrict__ bias, int K){
  int row = blockIdx.x;              // 0..2047
  int dd = row >> 10, gc = row & 1023;
  const float* src = (dd ? Wb : Wf) + (size_t)gc * K;
  unsigned short* dst = Bw + (size_t)row * K;
  for (int k = threadIdx.x * 4; k < K; k += 256){
    float4 v = *(const float4*)(src + k);
    unsigned lo = f2bf(v.x) | ((unsigned)f2bf(v.y) << 16);
    unsigned hi = f2bf(v.z) | ((unsigned)f2bf(v.w) << 16);
    *(uint2*)(dst + k) = make_uint2(lo, hi);
  }
  if (threadIdx.x == 0)
    bias[row] = dd ? (bihb[gc] + bhhb[gc]) : (bihf[gc] + bhhf[gc]);
}

// C[row=t*32+b][col 0..2047] = A[row][K] @ Bw[col][K]^T + bias[col], stored xg[t][col][b] bf16
__global__ __launch_bounds__(256) void gemm_xg(const unsigned short* __restrict__ A,
    const unsigned short* __restrict__ Bw, const float* __restrict__ bias,
    unsigned short* __restrict__ xg, int K){
  __shared__ __align__(16) unsigned short Al[128 * 64];
  __shared__ __align__(16) unsigned short Bl[128 * 64];
  const int tid = threadIdx.x;
  const int w = tid >> 6, l = tid & 63, q = l >> 4, cl = l & 15;
  const int bm = blockIdx.x >> 4, bn = blockIdx.x & 15;
  const int wm = w & 1, wn = w >> 1;
  f32x4 acc[4][4];
#pragma unroll
  for (int nt = 0; nt < 4; ++nt){
    float bv = bias[bn * 128 + wn * 64 + nt * 16 + cl];
#pragma unroll
    for (int mt = 0; mt < 4; ++mt) acc[mt][nt] = (f32x4){bv, bv, bv, bv};
  }
  const unsigned short* Ab = A + (size_t)(bm * 128) * K;
  const unsigned short* Bb = Bw + (size_t)(bn * 128) * K;
  for (int k0 = 0; k0 < K; k0 += 64){
#pragma unroll
    for (int i = 0; i < 4; ++i){
      int task = tid + i * 256;
      int row = task >> 3, ch = task & 7;
      int sw = ((ch ^ (row & 7)) * 8);
      *(uint4*)(&Al[row * 64 + sw]) = *(const uint4*)(Ab + (size_t)row * K + k0 + ch * 8);
      *(uint4*)(&Bl[row * 64 + sw]) = *(const uint4*)(Bb + (size_t)row * K + k0 + ch * 8);
    }
    __syncthreads();
#pragma unroll
    for (int kt2 = 0; kt2 < 2; ++kt2){
      short8 af[4], bfv[4];
#pragma unroll
      for (int mt = 0; mt < 4; ++mt){
        int row = wm * 64 + mt * 16 + cl;
        af[mt] = *(const short8*)(&Al[row * 64 + (((kt2 * 4 + q) ^ (row & 7)) * 8)]);
      }
#pragma unroll
      for (int nt = 0; nt < 4; ++nt){
        int n = wn * 64 + nt * 16 + cl;
        bfv[nt] = *(const short8*)(&Bl[n * 64 + (((kt2 * 4 + q) ^ (n & 7)) * 8)]);
      }
#pragma unroll
      for (int mt = 0; mt < 4; ++mt)
#pragma unroll
        for (int nt = 0; nt < 4; ++nt)
          acc[mt][nt] = __builtin_amdgcn_mfma_f32_16x16x32_bf16(af[mt], bfv[nt], acc[mt][nt], 0, 0, 0);
    }
    __syncthreads();
  }
#pragma unroll
  for (int mt = 0; mt < 4; ++mt){
    int row = bm * 128 + wm * 64 + mt * 16 + q * 4;
    int tt = row >> 5, bb = row & 31;
#pragma unroll
    for (int nt = 0; nt < 4; ++nt){
      int col = bn * 128 + wn * 64 + nt * 16 + cl;
      f32x4 v = acc[mt][nt];
      unsigned lo = f2bf(v[0]) | ((unsigned)f2bf(v[1]) << 16);
      unsigned hi = f2bf(v[2]) | ((unsigned)f2bf(v[3]) << 16);
      *(uint2*)(xg + ((size_t)tt * 2048 + col) * 32 + bb) = make_uint2(lo, hi);
    }
  }
}

// ---------------------------------------------------------------------------
// Recurrent core, pairwise-half design.
// 8 blocks x 512 threads. bid: ch = bid&1 (col-half, 128 h-cols), d = (bid>>1)&1
// (direction), g = bid>>2 (batch group of 16 -> M=16, full MFMA rows).
// Each wave owns 16 h-cols x 4 gates x K=256 of Whh in VGPRs (bfrag, 128 VGPR),
// ordered [0..3]=LOCAL k-tiles (own cols), [4..7]=REMOTE k-tiles (partner cols)
// so all loop indices are compile-time constant.
// Own-half h lives in LDS (row pad 272B -> conflict-free ds_read_b128, double
// buffered, one __syncthreads/step). Partner-half h goes through hx (LLC, sc1)
// with the tag-in-data protocol: u32 = (h_bf16<<16)|tag16, tag = t+1, 2 slots.
// Consumer waves poll partner words DIRECTLY into A-fragment registers (one
// base + imm offsets), strip tags with v_perm - no LDS relay, no relay sync.
// Poll loads issue first, local-half MFMAs run under them, then vmcnt(0)+check.
// xg preactivations are prefetched one step ahead (unroll 2 rotates xp/xn).
// ---------------------------------------------------------------------------
#define POLL8(EXTRA) \
  asm volatile( \
    "global_load_dwordx4 %0, %8, off sc1\n\t" \
    "global_load_dwordx4 %1, %8, off offset:16 sc1\n\t" \
    "global_load_dwordx4 %2, %8, off offset:128 sc1\n\t" \
    "global_load_dwordx4 %3, %8, off offset:144 sc1\n\t" \
    "global_load_dwordx4 %4, %8, off offset:256 sc1\n\t" \
    "global_load_dwordx4 %5, %8, off offset:272 sc1\n\t" \
    "global_load_dwordx4 %6, %8, off offset:384 sc1\n\t" \
    "global_load_dwordx4 %7, %8, off offset:400 sc1" EXTRA \
    : "=v"(pv0), "=v"(pv1), "=v"(pv2), "=v"(pv3), \
      "=v"(pv4), "=v"(pv5), "=v"(pv6), "=v"(pv7) \
    : "v"(pb) : "memory")

#define CHK() ( \
  xx = (pv0.x^tagv)|(pv0.y^tagv)|(pv0.z^tagv)|(pv0.w^tagv) \
     | (pv1.x^tagv)|(pv1.y^tagv)|(pv1.z^tagv)|(pv1.w^tagv) \
     | (pv2.x^tagv)|(pv2.y^tagv)|(pv2.z^tagv)|(pv2.w^tagv) \
     | (pv3.x^tagv)|(pv3.y^tagv)|(pv3.z^tagv)|(pv3.w^tagv) \
     | (pv4.x^tagv)|(pv4.y^tagv)|(pv4.z^tagv)|(pv4.w^tagv) \
     | (pv5.x^tagv)|(pv5.y^tagv)|(pv5.z^tagv)|(pv5.w^tagv) \
     | (pv6.x^tagv)|(pv6.y^tagv)|(pv6.z^tagv)|(pv6.w^tagv) \
     | (pv7.x^tagv)|(pv7.y^tagv)|(pv7.z^tagv)|(pv7.w^tagv), \
  __all((xx & 0xFFFFu) == 0u) )

#define RKT(RT, UA, UB) { \
  short8 ar; unsigned* arp = (unsigned*)&ar; \
  arp[0] = __builtin_amdgcn_perm(UA.y, UA.x, 0x07060302u); \
  arp[1] = __builtin_amdgcn_perm(UA.w, UA.z, 0x07060302u); \
  arp[2] = __builtin_amdgcn_perm(UB.y, UB.x, 0x07060302u); \
  arp[3] = __builtin_amdgcn_perm(UB.w, UB.z, 0x07060302u); \
  acc[0] = __builtin_amdgcn_mfma_f32_16x16x32_bf16(ar, bfrag[0][4 + RT], acc[0], 0, 0, 0); \
  acc[1] = __builtin_amdgcn_mfma_f32_16x16x32_bf16(ar, bfrag[1][4 + RT], acc[1], 0, 0, 0); \
  acc[2] = __builtin_amdgcn_mfma_f32_16x16x32_bf16(ar, bfrag[2][4 + RT], acc[2], 0, 0, 0); \
  acc[3] = __builtin_amdgcn_mfma_f32_16x16x32_bf16(ar, bfrag[3][4 + RT], acc[3], 0, 0, 0); }

__global__ __launch_bounds__(512, 2) void lstm_rec(const unsigned short* __restrict__ xg,
    const float* __restrict__ WhhF, const float* __restrict__ WhhB,
    const float* __restrict__ mask, unsigned* __restrict__ hx,
    unsigned short* __restrict__ houts, float* __restrict__ out,
    float* __restrict__ hnout, float* __restrict__ cnout, int layer){
  __shared__ __align__(16) unsigned short hbuf[2][16][136];  // own-half h, 272B row pad
  __shared__ __align__(16) float maskL[16384];               // [t(1024)][row(16)]
  const int tid = threadIdx.x;
  const int w = tid >> 6, l = tid & 63, q = l >> 4, cl = l & 15;
  const int bid = blockIdx.x;
  const int ch = bid & 1, d = (bid >> 1) & 1, g = bid >> 2;
  const float* __restrict__ Whh = d ? WhhB : WhhF;
  const int jj = ch * 128 + w * 16 + cl;     // hidden col owned by this lane (0..255)
  const int ph = ch ^ 1;
  const int ch4 = ch * 4, ph4 = ph * 4;

  // Whh B-fragments: [gate][p], p 0..3 = local k-tiles, 4..7 = remote k-tiles
  short8 bfrag[4][8];
#pragma unroll
  for (int gi = 0; gi < 4; ++gi){
    const float* wg = Whh + (size_t)(gi * 256 + jj) * 256 + q * 8;
#pragma unroll
    for (int p = 0; p < 8; ++p){
      int gk = (p < 4) ? (ch4 + p) : (ph4 + (p - 4));
      float4 x0 = *(const float4*)(wg + gk * 32);
      float4 x1 = *(const float4*)(wg + gk * 32 + 4);
      short8 f;
      f[0] = (short)f2bf(x0.x); f[1] = (short)f2bf(x0.y); f[2] = (short)f2bf(x0.z); f[3] = (short)f2bf(x0.w);
      f[4] = (short)f2bf(x1.x); f[5] = (short)f2bf(x1.y); f[6] = (short)f2bf(x1.z); f[7] = (short)f2bf(x1.w);
      bfrag[gi][p] = f;
    }
  }
  // mask -> LDS, [t][row16] so activation reads one f32x4 per lane
  for (int i = tid; i < 16384; i += 512){
    int tt = i >> 4, r = i & 15;
    maskL[i] = mask[(size_t)(g * 16 + r) * 1024 + tt];
  }
  __syncthreads();

  float cst[4] = {0.f, 0.f, 0.f, 0.f};
  unsigned* hxu = hx + (size_t)(d * 2 + g) * 8192;   // [slot(2)][row(16)][col(256)] u32
  const unsigned* plA = hxu + cl * 256 + ph * 128 + q * 8;  // consumer base, slot 0 (par==1)
  const unsigned* plB = plA + 4096;                         // slot 1 (par==0)
  unsigned* stA = hxu + (q * 4) * 256 + jj;                 // producer base, slot 0 (par==0)
  unsigned* stB = stA + 4096;
  const int bq = g * 16 + q * 4;
  const size_t dj = (size_t)d * 256 + jj;
  unsigned short* hob = houts + (size_t)bq * 512 + dj;      // + r*512 + ot*16384
  float* outb = out + (size_t)bq * 524288 + dj;             // + r*524288 + ot*512

  const ptrdiff_t tstep = d ? -65536 : 65536;
  const unsigned short* xcur = xg + (size_t)(d ? 1023 : 0) * 65536
                               + ((size_t)d * 1024 + jj) * 32 + g * 16 + q * 4;
  short4v xp[4], xn[4];
#pragma unroll
  for (int gi = 0; gi < 4; ++gi) xp[gi] = *(const short4v*)(xcur + gi * 8192);

#pragma unroll 2
  for (int t = 0; t < 1024; ++t){
    const int par = t & 1;
    const int ot = d ? (1023 - t) : t;
    f32x4 acc[4];
#pragma unroll
    for (int gi = 0; gi < 4; ++gi)
      acc[gi] = (f32x4){bf2f((unsigned short)xp[gi][0]), bf2f((unsigned short)xp[gi][1]),
                        bf2f((unsigned short)xp[gi][2]), bf2f((unsigned short)xp[gi][3])};
    if (t > 0){
      const unsigned* pb = par ? plA : plB;
      uint4 pv0, pv1, pv2, pv3, pv4, pv5, pv6, pv7;
      POLL8("");                                  // issue polls, no wait
      // local half from LDS while polls are in flight
      const char* lbp = (const char*)(&hbuf[par ^ 1][0][0]) + cl * 272 + q * 16;
#pragma unroll
      for (int lt = 0; lt < 4; ++lt){
        short8 a = *(const short8*)(lbp + lt * 64);
        acc[0] = __builtin_amdgcn_mfma_f32_16x16x32_bf16(a, bfrag[0][lt], acc[0], 0, 0, 0);
        acc[1] = __builtin_amdgcn_mfma_f32_16x16x32_bf16(a, bfrag[1][lt], acc[1], 0, 0, 0);
        acc[2] = __builtin_amdgcn_mfma_f32_16x16x32_bf16(a, bfrag[2][lt], acc[2], 0, 0, 0);
        acc[3] = __builtin_amdgcn_mfma_f32_16x16x32_bf16(a, bfrag[3][lt], acc[3], 0, 0, 0);
      }
      asm volatile("s_waitcnt vmcnt(0)" ::: "memory");
      __builtin_amdgcn_sched_barrier(0);
      const unsigned tagv = (unsigned)t;
      unsigned xx;
      if (!CHK()){
        do{
          POLL8("\n\ts_waitcnt vmcnt(0)");
          __builtin_amdgcn_sched_barrier(0);
        } while (!CHK());
      }
      if (t < 1023){
#pragma unroll
        for (int gi = 0; gi < 4; ++gi) xn[gi] = *(const short4v*)(xcur + tstep + gi * 8192);
      }
      RKT(0, pv0, pv1);
      RKT(1, pv2, pv3);
      RKT(2, pv4, pv5);
      RKT(3, pv6, pv7);
    } else {
#pragma unroll
      for (int gi = 0; gi < 4; ++gi) xn[gi] = *(const short4v*)(xcur + tstep + gi * 8192);
    }
    // activation: lane (q,cl) holds col jj, rows 4q..4q+3 of the 16-row tile
    f32x4 mv = *(const f32x4*)(&maskL[ot * 16 + q * 4]);
    float hv[4]; unsigned short hb[4];
#pragma unroll
    for (int r = 0; r < 4; ++r){
      float ig = sigf(acc[0][r]);
      float fg = sigf(acc[1][r]);
      float gg = tanhf_(acc[2][r]);
      float og = sigf(acc[3][r]);
      float cn = fg * cst[r] + ig * gg;
      float hn = og * tanhf_(cn);
      float m = mv[r];
      hn *= m; cn *= m;
      cst[r] = cn; hv[r] = hn; hb[r] = f2bf(hn);
    }
    // partner-visible stores first (latency-critical), then local LDS, then outputs
    unsigned* sw = par ? stB : stA;
    const unsigned tagn = (unsigned)(t + 1);
#pragma unroll
    for (int r = 0; r < 4; ++r)
      __hip_atomic_store(sw + r * 256, ((unsigned)hb[r] << 16) | tagn,
                         __ATOMIC_RELAXED, __HIP_MEMORY_SCOPE_AGENT);
#pragma unroll
    for (int r = 0; r < 4; ++r) hbuf[par][q * 4 + r][w * 16 + cl] = hb[r];
    if (layer == 0){
#pragma unroll
      for (int r = 0; r < 4; ++r) hob[(size_t)ot * 16384 + r * 512] = hb[r];
    } else {
#pragma unroll
      for (int r = 0; r < 4; ++r) outb[(size_t)r * 524288 + (size_t)ot * 512] = hv[r];
    }
    if (t == 1023){
#pragma unroll
      for (int r = 0; r < 4; ++r){
        size_t bo = (size_t)(layer * 32 + bq + r) * 512 + dj;
        hnout[bo] = hv[r];
        cnout[bo] = cst[r];
      }
    }
    __syncthreads();
#pragma unroll
    for (int gi = 0; gi < 4; ++gi) xp[gi] = xn[gi];
    xcur += tstep;
  }
}

extern "C" void kernel_launch(void* const* d_in, const int* in_sizes, int n_in,
                              void* d_out, int out_size, void* d_ws, size_t ws_size,
                              hipStream_t stream){
  const float* inputs  = (const float*)d_in[0];
  const float* mask    = (const float*)d_in[1];
  const float* l0f_Wih = (const float*)d_in[2];
  const float* l0f_Whh = (const float*)d_in[3];
  const float* l0f_bih = (const float*)d_in[4];
  const float* l0f_bhh = (const float*)d_in[5];
  const float* l0b_Wih = (const float*)d_in[6];
  const float* l0b_Whh = (const float*)d_in[7];
  const float* l0b_bih = (const float*)d_in[8];
  const float* l0b_bhh = (const float*)d_in[9];
  const float* l1f_Wih = (const float*)d_in[10];
  const float* l1f_Whh = (const float*)d_in[11];
  const float* l1f_bih = (const float*)d_in[12];
  const float* l1f_bhh = (const float*)d_in[13];
  const float* l1b_Wih = (const float*)d_in[14];
  const float* l1b_Whh = (const float*)d_in[15];
  const float* l1b_bih = (const float*)d_in[16];
  const float* l1b_bhh = (const float*)d_in[17];

  char* ws = (char*)d_ws;
  unsigned short* xg   = (unsigned short*)(ws);                 // [1024][2048][32] bf16, 134217728 B
  unsigned short* xbf  = (unsigned short*)(ws + 134217728);     // [32768][256]  bf16, 16777216 B
  unsigned short* hout = (unsigned short*)(ws + 150994944);     // [32768][512]  bf16, 33554432 B
  unsigned short* B0   = (unsigned short*)(ws + 184549376);     // [2048][256]   bf16, 1048576 B
  unsigned short* B1   = (unsigned short*)(ws + 185597952);     // [2048][512]   bf16, 2097152 B
  float* bias0         = (float*)(ws + 187695104);              // [2048] f32
  float* bias1         = (float*)(ws + 187703296);              // [2048] f32
  unsigned* hx         = (unsigned*)(ws + 187711488);           // 2 layers x [4 units][2 slots][16][256] u32

  float* out   = (float*)d_out;          // [32][1024][512]
  float* hnout = out + 16777216;         // [2][32][512]
  float* cnout = hnout + 32768;          // [2][32][512]

  hipMemsetAsync(hx, 0, 262144, stream);  // tag16 = 0, never matches tags 1..1024
  cast_x<<<32768, 64, 0, stream>>>(inputs, xbf);
  cast_w<<<2048, 64, 0, stream>>>(l0f_Wih, l0b_Wih, l0f_bih, l0f_bhh, l0b_bih, l0b_bhh, B0, bias0, 256);
  cast_w<<<2048, 64, 0, stream>>>(l1f_Wih, l1b_Wih, l1f_bih, l1f_bhh, l1b_bih, l1b_bhh, B1, bias1, 512);
  gemm_xg<<<4096, 256, 0, stream>>>(xbf, B0, bias0, xg, 256);
  lstm_rec<<<8, 512, 0, stream>>>(xg, l0f_Whh, l0b_Whh, mask, hx, hout, nullptr, hnout, cnout, 0);
  gemm_xg<<<4096, 256, 0, stream>>>(hout, B1, bias1, xg, 512);
  lstm_rec<<<8, 512, 0, stream>>>(xg, l1f_Whh, l1b_Whh, mask, hx + 32768, nullptr, out, hnout, cnout, 1);
}

// Round 2
// 4524.883 us; speedup vs baseline: 1.5246x; 1.5246x over previous
//
#include <hip/hip_runtime.h>
#include <cstddef>

typedef __attribute__((ext_vector_type(8))) short short8;
typedef __attribute__((ext_vector_type(4))) short short4v;
typedef __attribute__((ext_vector_type(4))) float f32x4;

__device__ __forceinline__ unsigned short f2bf(float f){
  unsigned u = __builtin_bit_cast(unsigned, f);
  u += 0x7FFFu + ((u >> 16) & 1u);          // round-to-nearest-even
  return (unsigned short)(u >> 16);
}
__device__ __forceinline__ float bf2f(unsigned short h){
  unsigned u = ((unsigned)h) << 16;
  return __builtin_bit_cast(float, u);
}
__device__ __forceinline__ float sigf(float x){
  return __builtin_amdgcn_rcpf(1.0f + __builtin_amdgcn_exp2f(-1.4426950408889634f * x));
}
__device__ __forceinline__ float tanhf_(float x){
  return 1.0f - 2.0f * __builtin_amdgcn_rcpf(1.0f + __builtin_amdgcn_exp2f(2.8853900817779268f * x));
}

// inputs [32][1024][256] fp32 -> xbf [t*32+b][256] bf16
__global__ __launch_bounds__(64) void cast_x(const float* __restrict__ in, unsigned short* __restrict__ xb){
  int blk = blockIdx.x;              // b*1024 + t
  int t = blk & 1023, b = blk >> 10;
  int k = threadIdx.x * 4;
  float4 v = *(const float4*)(in + (size_t)blk * 256 + k);
  unsigned lo = f2bf(v.x) | ((unsigned)f2bf(v.y) << 16);
  unsigned hi = f2bf(v.z) | ((unsigned)f2bf(v.w) << 16);
  *(uint2*)(xb + ((size_t)t * 32 + b) * 256 + k) = make_uint2(lo, hi);
}

// Wih (fw,bw) fp32 -> Bw [2048][K] bf16 (row = dir*1024 + gatecol), bias[row] = bih+bhh
__global__ __launch_bounds__(64) void cast_w(const float* __restrict__ Wf, const float* __restrict__ Wb,
    const float* __restrict__ bihf, const float* __restrict__ bhhf,
    const float* __restrict__ bihb, const float* __restrict__ bhhb,
    unsigned short* __restrict__ Bw, float* __restrict__ bias, int K){
  int row = blockIdx.x;              // 0..2047
  int dd = row >> 10, gc = row & 1023;
  const float* src = (dd ? Wb : Wf) + (size_t)gc * K;
  unsigned short* dst = Bw + (size_t)row * K;
  for (int k = threadIdx.x * 4; k < K; k += 256){
    float4 v = *(const float4*)(src + k);
    unsigned lo = f2bf(v.x) | ((unsigned)f2bf(v.y) << 16);
    unsigned hi = f2bf(v.z) | ((unsigned)f2bf(v.w) << 16);
    *(uint2*)(dst + k) = make_uint2(lo, hi);
  }
  if (threadIdx.x == 0)
    bias[row] = dd ? (bihb[gc] + bhhb[gc]) : (bihf[gc] + bhhf[gc]);
}

// C[row=t*32+b][col 0..2047] = A[row][K] @ Bw[col][K]^T + bias[col], stored xg[t][col][b] bf16
__global__ __launch_bounds__(256) void gemm_xg(const unsigned short* __restrict__ A,
    const unsigned short* __restrict__ Bw, const float* __restrict__ bias,
    unsigned short* __restrict__ xg, int K){
  __shared__ __align__(16) unsigned short Al[128 * 64];
  __shared__ __align__(16) unsigned short Bl[128 * 64];
  const int tid = threadIdx.x;
  const int w = tid >> 6, l = tid & 63, q = l >> 4, cl = l & 15;
  const int bm = blockIdx.x >> 4, bn = blockIdx.x & 15;
  const int wm = w & 1, wn = w >> 1;
  f32x4 acc[4][4];
#pragma unroll
  for (int nt = 0; nt < 4; ++nt){
    float bv = bias[bn * 128 + wn * 64 + nt * 16 + cl];
#pragma unroll
    for (int mt = 0; mt < 4; ++mt) acc[mt][nt] = (f32x4){bv, bv, bv, bv};
  }
  const unsigned short* Ab = A + (size_t)(bm * 128) * K;
  const unsigned short* Bb = Bw + (size_t)(bn * 128) * K;
  for (int k0 = 0; k0 < K; k0 += 64){
#pragma unroll
    for (int i = 0; i < 4; ++i){
      int task = tid + i * 256;
      int row = task >> 3, ch = task & 7;
      int sw = ((ch ^ (row & 7)) * 8);
      *(uint4*)(&Al[row * 64 + sw]) = *(const uint4*)(Ab + (size_t)row * K + k0 + ch * 8);
      *(uint4*)(&Bl[row * 64 + sw]) = *(const uint4*)(Bb + (size_t)row * K + k0 + ch * 8);
    }
    __syncthreads();
#pragma unroll
    for (int kt2 = 0; kt2 < 2; ++kt2){
      short8 af[4], bfv[4];
#pragma unroll
      for (int mt = 0; mt < 4; ++mt){
        int row = wm * 64 + mt * 16 + cl;
        af[mt] = *(const short8*)(&Al[row * 64 + (((kt2 * 4 + q) ^ (row & 7)) * 8)]);
      }
#pragma unroll
      for (int nt = 0; nt < 4; ++nt){
        int n = wn * 64 + nt * 16 + cl;
        bfv[nt] = *(const short8*)(&Bl[n * 64 + (((kt2 * 4 + q) ^ (n & 7)) * 8)]);
      }
#pragma unroll
      for (int mt = 0; mt < 4; ++mt)
#pragma unroll
        for (int nt = 0; nt < 4; ++nt)
          acc[mt][nt] = __builtin_amdgcn_mfma_f32_16x16x32_bf16(af[mt], bfv[nt], acc[mt][nt], 0, 0, 0);
    }
    __syncthreads();
  }
#pragma unroll
  for (int mt = 0; mt < 4; ++mt){
    int row = bm * 128 + wm * 64 + mt * 16 + q * 4;
    int tt = row >> 5, bb = row & 31;
#pragma unroll
    for (int nt = 0; nt < 4; ++nt){
      int col = bn * 128 + wn * 64 + nt * 16 + cl;
      f32x4 v = acc[mt][nt];
      unsigned lo = f2bf(v[0]) | ((unsigned)f2bf(v[1]) << 16);
      unsigned hi = f2bf(v[2]) | ((unsigned)f2bf(v[3]) << 16);
      *(uint2*)(xg + ((size_t)tt * 2048 + col) * 32 + bb) = make_uint2(lo, hi);
    }
  }
}

// ---------------------------------------------------------------------------
// Recurrent core, pairwise-half design with LDS relay (v2).
// 8 blocks x 512 threads. bid: ch = bid&1 (col-half, 128 h-cols), d = (bid>>1)&1
// (direction), g = bid>>2 (batch group of 16 -> M=16, full MFMA rows).
// Each wave owns 16 h-cols x 4 gates x K=256 of Whh in VGPRs (bfrag, 128 regs),
// p 0..3 = LOCAL k-tiles (own half), 4..7 = REMOTE k-tiles (partner half).
// Own-half h: LDS hloc[2] (written by producers end of step t, read step t+1
// after the mid-step barrier). Partner half: hx (LLC, sc1) tag-in-data protocol
// (u32 = h_bf16<<16 | tag16, tag = t+1, 2 slots, reuse race-free via the
// tag-verified dependency chain). Each wave polls ONLY its 2 rows x 128 cols
// (one dwordx4 per lane - no redundant polling, 1-load retry), strips tags with
// v_perm, relays into hrem[2], ONE __syncthreads, then all waves build all 8
// A-ktiles from LDS and run 32 MFMAs. xg preactivations prefetched one step
// ahead (unroll 2 rotates xp/xn) so HBM latency never sits in the poll wait.
// Single barrier/step is race-free: all LDS A-reads are post-barrier(t), all
// LDS writes for step t+1 are pre-barrier(t+1), buffers are double-buffered.
// ---------------------------------------------------------------------------
#define POLL1(EXTRA) \
  asm volatile("global_load_dwordx4 %0, %1, off sc1" EXTRA \
    : "=v"(pv) : "v"(pb) : "memory")

#define CHK() ( \
  xx = (pv.x ^ tagv) | (pv.y ^ tagv) | (pv.z ^ tagv) | (pv.w ^ tagv), \
  __all((xx & 0xFFFFu) == 0u) )

__global__ __launch_bounds__(512, 1) void lstm_rec(const unsigned short* __restrict__ xg,
    const float* __restrict__ WhhF, const float* __restrict__ WhhB,
    const float* __restrict__ mask, unsigned* __restrict__ hx,
    unsigned short* __restrict__ houts, float* __restrict__ out,
    float* __restrict__ hnout, float* __restrict__ cnout, int layer){
  __shared__ __align__(16) unsigned short hloc[2][16][136];  // own-half h, 272B row stride
  __shared__ __align__(16) unsigned short hrem[2][16][136];  // relayed partner-half h
  __shared__ __align__(16) float maskL[16384];               // [t(1024)][row(16)]
  const int tid = threadIdx.x;
  const int w = tid >> 6, l = tid & 63, q = l >> 4, cl = l & 15;
  const int bid = blockIdx.x;
  const int ch = bid & 1, d = (bid >> 1) & 1, g = bid >> 2;
  const float* __restrict__ Whh = d ? WhhB : WhhF;
  const int jj = ch * 128 + w * 16 + cl;     // hidden col owned by this lane (0..255)
  const int ph = ch ^ 1;
  const int ch4 = ch * 4, ph4 = ph * 4;

  // Whh B-fragments: [gate][p], p 0..3 = local k-tiles, 4..7 = remote k-tiles
  short8 bfrag[4][8];
#pragma unroll
  for (int gi = 0; gi < 4; ++gi){
    const float* wg = Whh + (size_t)(gi * 256 + jj) * 256 + q * 8;
#pragma unroll
    for (int p = 0; p < 8; ++p){
      int gk = (p < 4) ? (ch4 + p) : (ph4 + (p - 4));
      float4 x0 = *(const float4*)(wg + gk * 32);
      float4 x1 = *(const float4*)(wg + gk * 32 + 4);
      short8 f;
      f[0] = (short)f2bf(x0.x); f[1] = (short)f2bf(x0.y); f[2] = (short)f2bf(x0.z); f[3] = (short)f2bf(x0.w);
      f[4] = (short)f2bf(x1.x); f[5] = (short)f2bf(x1.y); f[6] = (short)f2bf(x1.z); f[7] = (short)f2bf(x1.w);
      bfrag[gi][p] = f;
    }
  }
  // mask -> LDS, [t][row16] so activation reads one f32x4 per lane
  for (int i = tid; i < 16384; i += 512){
    int tt = i >> 4, r = i & 15;
    maskL[i] = mask[(size_t)(g * 16 + r) * 1024 + tt];
  }
  __syncthreads();

  float cst[4] = {0.f, 0.f, 0.f, 0.f};
  unsigned* hxu = hx + (size_t)(d * 2 + g) * 8192;   // [slot(2)][row(16)][col(256)] u32
  // poll geometry: wave w owns rows {2w, 2w+1}; lane covers 4 cols of partner half
  const int rr = 2 * w + (l >> 5);
  const int cc = l & 31;
  const unsigned* plA = hxu + rr * 256 + ph * 128 + cc * 4;  // slot 0 (polled when par==1)
  const unsigned* plB = plA + 4096;                          // slot 1 (polled when par==0)
  unsigned* stA = hxu + (q * 4) * 256 + jj;                  // producer base, slot 0 (par==0)
  unsigned* stB = stA + 4096;
  const int bq = g * 16 + q * 4;
  const size_t dj = (size_t)d * 256 + jj;
  unsigned short* hob = houts + (size_t)bq * 512 + dj;      // + r*512 + ot*16384
  float* outb = out + (size_t)bq * 524288 + dj;             // + r*524288 + ot*512

  const ptrdiff_t tstep = d ? -65536 : 65536;
  const unsigned short* xcur = xg + (size_t)(d ? 1023 : 0) * 65536
                               + ((size_t)d * 1024 + jj) * 32 + g * 16 + q * 4;
  short4v xp[4], xn[4];
#pragma unroll
  for (int gi = 0; gi < 4; ++gi) xp[gi] = *(const short4v*)(xcur + gi * 8192);

#pragma unroll 2
  for (int t = 0; t < 1024; ++t){
    const int par = t & 1;
    const int ot = d ? (1023 - t) : t;
    f32x4 acc[4];
    if (t > 0){
      const unsigned* pb = par ? plA : plB;
      uint4 pv;
      POLL1("");                                  // issue poll, no wait
      // acc init (VALU) sits under the poll latency
#pragma unroll
      for (int gi = 0; gi < 4; ++gi)
        acc[gi] = (f32x4){bf2f((unsigned short)xp[gi][0]), bf2f((unsigned short)xp[gi][1]),
                          bf2f((unsigned short)xp[gi][2]), bf2f((unsigned short)xp[gi][3])};
      asm volatile("s_waitcnt vmcnt(0)" ::: "memory");
      __builtin_amdgcn_sched_barrier(0);
      const unsigned tagv = (unsigned)t;
      unsigned xx;
      if (!CHK()){
        do{
          POLL1("\n\ts_waitcnt vmcnt(0)");
          __builtin_amdgcn_sched_barrier(0);
        } while (!CHK());
      }
      // next-step xg prefetch (issued after poll wait so it never blocks it)
      if (t < 1023){
#pragma unroll
        for (int gi = 0; gi < 4; ++gi) xn[gi] = *(const short4v*)(xcur + tstep + gi * 8192);
      }
      // relay: strip tags, write this wave's 2 rows into hrem
      {
        unsigned lo = __builtin_amdgcn_perm(pv.y, pv.x, 0x07060302u);
        unsigned hi = __builtin_amdgcn_perm(pv.w, pv.z, 0x07060302u);
        *(uint2*)(&hrem[par][rr][cc * 4]) = make_uint2(lo, hi);
      }
      __syncthreads();
      // all 8 A-ktiles from LDS: local half (written last step) + relayed remote
      const unsigned short* lb = &hloc[par ^ 1][0][0];
      const unsigned short* rb = &hrem[par][0][0];
      const int ao = cl * 136 + q * 8;
#pragma unroll
      for (int ktl = 0; ktl < 4; ++ktl){
        short8 a = *(const short8*)(lb + ao + ktl * 32);
        acc[0] = __builtin_amdgcn_mfma_f32_16x16x32_bf16(a, bfrag[0][ktl], acc[0], 0, 0, 0);
        acc[1] = __builtin_amdgcn_mfma_f32_16x16x32_bf16(a, bfrag[1][ktl], acc[1], 0, 0, 0);
        acc[2] = __builtin_amdgcn_mfma_f32_16x16x32_bf16(a, bfrag[2][ktl], acc[2], 0, 0, 0);
        acc[3] = __builtin_amdgcn_mfma_f32_16x16x32_bf16(a, bfrag[3][ktl], acc[3], 0, 0, 0);
      }
#pragma unroll
      for (int ktl = 0; ktl < 4; ++ktl){
        short8 a = *(const short8*)(rb + ao + ktl * 32);
        acc[0] = __builtin_amdgcn_mfma_f32_16x16x32_bf16(a, bfrag[0][4 + ktl], acc[0], 0, 0, 0);
        acc[1] = __builtin_amdgcn_mfma_f32_16x16x32_bf16(a, bfrag[1][4 + ktl], acc[1], 0, 0, 0);
        acc[2] = __builtin_amdgcn_mfma_f32_16x16x32_bf16(a, bfrag[2][4 + ktl], acc[2], 0, 0, 0);
        acc[3] = __builtin_amdgcn_mfma_f32_16x16x32_bf16(a, bfrag[3][4 + ktl], acc[3], 0, 0, 0);
      }
    } else {
#pragma unroll
      for (int gi = 0; gi < 4; ++gi)
        acc[gi] = (f32x4){bf2f((unsigned short)xp[gi][0]), bf2f((unsigned short)xp[gi][1]),
                          bf2f((unsigned short)xp[gi][2]), bf2f((unsigned short)xp[gi][3])};
#pragma unroll
      for (int gi = 0; gi < 4; ++gi) xn[gi] = *(const short4v*)(xcur + tstep + gi * 8192);
    }
    // activation: lane (q,cl) holds col jj, rows 4q..4q+3 of the 16-row tile
    f32x4 mv = *(const f32x4*)(&maskL[ot * 16 + q * 4]);
    float hv[4]; unsigned short hb[4];
#pragma unroll
    for (int r = 0; r < 4; ++r){
      float ig = sigf(acc[0][r]);
      float fg = sigf(acc[1][r]);
      float gg = tanhf_(acc[2][r]);
      float og = sigf(acc[3][r]);
      float cn = fg * cst[r] + ig * gg;
      float hn = og * tanhf_(cn);
      float m = mv[r];
      hn *= m; cn *= m;
      cst[r] = cn; hv[r] = hn; hb[r] = f2bf(hn);
    }
    // partner-visible stores first (latency-critical), then local LDS, then outputs
    unsigned* sw = par ? stB : stA;
    const unsigned tagn = (unsigned)(t + 1);
#pragma unroll
    for (int r = 0; r < 4; ++r)
      __hip_atomic_store(sw + r * 256, ((unsigned)hb[r] << 16) | tagn,
                         __ATOMIC_RELAXED, __HIP_MEMORY_SCOPE_AGENT);
#pragma unroll
    for (int r = 0; r < 4; ++r) hloc[par][q * 4 + r][w * 16 + cl] = hb[r];
    if (layer == 0){
#pragma unroll
      for (int r = 0; r < 4; ++r) hob[(size_t)ot * 16384 + r * 512] = hb[r];
    } else {
#pragma unroll
      for (int r = 0; r < 4; ++r) outb[(size_t)r * 524288 + (size_t)ot * 512] = hv[r];
    }
    if (t == 1023){
#pragma unroll
      for (int r = 0; r < 4; ++r){
        size_t bo = (size_t)(layer * 32 + bq + r) * 512 + dj;
        hnout[bo] = hv[r];
        cnout[bo] = cst[r];
      }
    }
    if (t < 1023){
#pragma unroll
      for (int gi = 0; gi < 4; ++gi) xp[gi] = xn[gi];
    }
    xcur += tstep;
  }
}

extern "C" void kernel_launch(void* const* d_in, const int* in_sizes, int n_in,
                              void* d_out, int out_size, void* d_ws, size_t ws_size,
                              hipStream_t stream){
  const float* inputs  = (const float*)d_in[0];
  const float* mask    = (const float*)d_in[1];
  const float* l0f_Wih = (const float*)d_in[2];
  const float* l0f_Whh = (const float*)d_in[3];
  const float* l0f_bih = (const float*)d_in[4];
  const float* l0f_bhh = (const float*)d_in[5];
  const float* l0b_Wih = (const float*)d_in[6];
  const float* l0b_Whh = (const float*)d_in[7];
  const float* l0b_bih = (const float*)d_in[8];
  const float* l0b_bhh = (const float*)d_in[9];
  const float* l1f_Wih = (const float*)d_in[10];
  const float* l1f_Whh = (const float*)d_in[11];
  const float* l1f_bih = (const float*)d_in[12];
  const float* l1f_bhh = (const float*)d_in[13];
  const float* l1b_Wih = (const float*)d_in[14];
  const float* l1b_Whh = (const float*)d_in[15];
  const float* l1b_bih = (const float*)d_in[16];
  const float* l1b_bhh = (const float*)d_in[17];

  char* ws = (char*)d_ws;
  unsigned short* xg   = (unsigned short*)(ws);                 // [1024][2048][32] bf16, 134217728 B
  unsigned short* xbf  = (unsigned short*)(ws + 134217728);     // [32768][256]  bf16, 16777216 B
  unsigned short* hout = (unsigned short*)(ws + 150994944);     // [32768][512]  bf16, 33554432 B
  unsigned short* B0   = (unsigned short*)(ws + 184549376);     // [2048][256]   bf16, 1048576 B
  unsigned short* B1   = (unsigned short*)(ws + 185597952);     // [2048][512]   bf16, 2097152 B
  float* bias0         = (float*)(ws + 187695104);              // [2048] f32
  float* bias1         = (float*)(ws + 187703296);              // [2048] f32
  unsigned* hx         = (unsigned*)(ws + 187711488);           // 2 layers x [4 units][2 slots][16][256] u32

  float* out   = (float*)d_out;          // [32][1024][512]
  float* hnout = out + 16777216;         // [2][32][512]
  float* cnout = hnout + 32768;          // [2][32][512]

  hipMemsetAsync(hx, 0, 262144, stream);  // tag16 = 0, never matches tags 1..1024
  cast_x<<<32768, 64, 0, stream>>>(inputs, xbf);
  cast_w<<<2048, 64, 0, stream>>>(l0f_Wih, l0b_Wih, l0f_bih, l0f_bhh, l0b_bih, l0b_bhh, B0, bias0, 256);
  cast_w<<<2048, 64, 0, stream>>>(l1f_Wih, l1b_Wih, l1f_bih, l1f_bhh, l1b_bih, l1b_bhh, B1, bias1, 512);
  gemm_xg<<<4096, 256, 0, stream>>>(xbf, B0, bias0, xg, 256);
  lstm_rec<<<8, 512, 0, stream>>>(xg, l0f_Whh, l0b_Whh, mask, hx, hout, nullptr, hnout, cnout, 0);
  gemm_xg<<<4096, 256, 0, stream>>>(hout, B1, bias1, xg, 512);
  lstm_rec<<<8, 512, 0, stream>>>(xg, l1f_Whh, l1b_Whh, mask, hx + 32768, nullptr, out, hnout, cnout, 1);
}